// Round 2
// baseline (1055.791 us; speedup 1.0000x reference)
//
#include <hip/hip_runtime.h>

// NCN fused: 4 sequential modules, wave-per-chain (b,h,c), in-place y-sequence
// through d_out. Broadcast via v_readlane (no LDS), W in 16 named float4 regs.
// x: [8,4096,1024] f32, xa: [8,8,1024] f32, W: [4,16,64,64] f32.
// out = concat(final x [8,4096,1024], final xa [8,8,1024]).

constexpr int B  = 8;
constexpr int T  = 4096;
constexpr int D  = 1024;
constexpr int H  = 16;
constexpr int DH = 64;
constexpr int NC = 8;
constexpr int NM = 4;
constexpr int STEPS = T / NC;  // 512

// broadcast lane l of v to all lanes (v_readlane_b32 -> SGPR, used as FMA src)
#define RL(v, l) __int_as_float(__builtin_amdgcn_readlane(__float_as_int(v), (l)))

__global__ __launch_bounds__(256, 1)
void ncn_fused(const float* __restrict__ x, const float* __restrict__ xa,
               const float* __restrict__ w, float* __restrict__ out) {
  const int lane = threadIdx.x & 63;
  const int wv   = threadIdx.x >> 6;
  const int ch   = blockIdx.x * 4 + wv;   // chain id 0..1023
  const int c    = ch & (NC - 1);         // cache slot
  const int bh   = ch >> 3;
  const int h    = bh & (H - 1);
  const int b    = bh >> 4;

  float* outx  = out;                       // [B,T,D]
  float* outya = out + (size_t)B * T * D;   // [B,NC,D]

  const size_t base = (size_t)b * T * D + (size_t)h * DH + lane;

  // cache carry: module 0 from xa; modules 1..3 carry previous module's final y
  float y = xa[((size_t)b * NC + c) * D + (size_t)h * DH + lane];

  for (int m = 0; m < NM; ++m) {
    // W column for this lane as 16 NAMED float4s (forced register residency):
    // w{k}.{x,y,z,w} = W[m][h][4k+j][lane]
    const float* wp = w + (size_t)(m * H + h) * DH * DH + lane;
#define LW(k) const float4 w##k = make_float4( \
      wp[(size_t)(4*(k)+0)*DH], wp[(size_t)(4*(k)+1)*DH], \
      wp[(size_t)(4*(k)+2)*DH], wp[(size_t)(4*(k)+3)*DH]);
    LW(0) LW(1) LW(2) LW(3) LW(4) LW(5) LW(6) LW(7)
    LW(8) LW(9) LW(10) LW(11) LW(12) LW(13) LW(14) LW(15)
#undef LW

    const float* inp = (m == 0) ? x : outx;  // in-place after module 0

    // Module boundary: our previous-module stores must complete before we
    // read the same addresses back (same wave, disjoint across waves).
    asm volatile("s_waitcnt vmcnt(0)" ::: "memory");

    // input prefetch pipeline, depth 3 (covers HBM-miss latency)
    auto addr = [&](int i) {
      const int ii = (i < STEPS) ? i : (STEPS - 1);
      return base + (size_t)(c + NC * ii) * D;
    };
    float vin = inp[addr(0)];
    float vA  = inp[addr(1)];
    float vB  = inp[addr(2)];

    int t = c;
    for (int i = 0; i < STEPS; ++i) {
      const float vN = inp[addr(i + 3)];

      // mix[lane] = sum_d in[d] * W[d][lane], broadcast via readlane
      float a0 = 0.f, a1 = 0.f, a2 = 0.f, a3 = 0.f;
#define FW(k) \
      a0 = fmaf(RL(vin, 4*(k)+0), w##k.x, a0); \
      a1 = fmaf(RL(vin, 4*(k)+1), w##k.y, a1); \
      a2 = fmaf(RL(vin, 4*(k)+2), w##k.z, a2); \
      a3 = fmaf(RL(vin, 4*(k)+3), w##k.w, a3);
      FW(0) FW(1) FW(2) FW(3) FW(4) FW(5) FW(6) FW(7)
      FW(8) FW(9) FW(10) FW(11) FW(12) FW(13) FW(14) FW(15)
#undef FW
      const float mix = (a0 + a1) + (a2 + a3);

      // y = tanh(0.5*y + 0.5*mix) = 1 - 2/(e^z + 1), z = y + mix
      const float z  = y + mix;
      const float ex = __expf(z);
      y = 1.0f - 2.0f * __builtin_amdgcn_rcpf(ex + 1.0f);

      outx[base + (size_t)t * D] = y;

      vin = vA; vA = vB; vB = vN;
      t += NC;
    }
  }

  outya[((size_t)b * NC + c) * D + (size_t)h * DH + lane] = y;
}

extern "C" void kernel_launch(void* const* d_in, const int* in_sizes, int n_in,
                              void* d_out, int out_size, void* d_ws, size_t ws_size,
                              hipStream_t stream) {
  (void)in_sizes; (void)n_in; (void)d_ws; (void)ws_size; (void)out_size;
  const float* x  = (const float*)d_in[0];
  const float* xa = (const float*)d_in[1];
  const float* w  = (const float*)d_in[2];
  float* out = (float*)d_out;

  dim3 grid(256), block(256);
  hipLaunchKernelGGL(ncn_fused, grid, block, 0, stream, x, xa, w, out);
}

// Round 3
// 724.352 us; speedup vs baseline: 1.4576x; 1.4576x over previous
//
#include <hip/hip_runtime.h>

// NCN fused: 4 sequential modules, wave-per-chain (b,h,c), in-place y stream
// through d_out. Input broadcast via double-buffered LDS uniform-address
// ds_read_b128; mix via v_pk_fma_f32 (v4f); W pinned in arch VGPRs.

typedef float v4f __attribute__((ext_vector_type(4)));

constexpr int B  = 8;
constexpr int T  = 4096;
constexpr int D  = 1024;
constexpr int H  = 16;
constexpr int DH = 64;
constexpr int NC = 8;
constexpr int NM = 4;
constexpr int STEPS = T / NC;   // 512
constexpr int NCD   = NC * D;   // element stride per step

__global__ __launch_bounds__(256, 1)
void ncn_fused(const float* __restrict__ x, const float* __restrict__ xa,
               const float* __restrict__ w, float* __restrict__ out) {
  __shared__ alignas(16) float bc[4][2][DH];

  const int lane = threadIdx.x & 63;
  const int wv   = __builtin_amdgcn_readfirstlane(threadIdx.x >> 6);
  const int ch   = __builtin_amdgcn_readfirstlane(blockIdx.x) * 4 + wv;
  const int c    = ch & (NC - 1);
  const int bh   = ch >> 3;
  const int h    = bh & (H - 1);
  const int b    = bh >> 4;

  float* outx  = out;                       // [B,T,D]
  float* outya = out + (size_t)B * T * D;   // [B,NC,D]

  // wave-uniform element offset of this chain's step-0 row
  const size_t ubase = (size_t)b * T * D + (size_t)h * DH + (size_t)c * D;

  float y = xa[((size_t)b * NC + c) * D + (size_t)h * DH + lane];

  float* const b0 = &bc[wv][0][0];
  float* const b1 = &bc[wv][1][0];

  for (int m = 0; m < NM; ++m) {
    // W column for this lane: W{k}[j] = W[m][h][4k+j][lane]
    const float* wp = w + (size_t)(m * H + h) * DH * DH + lane;
#define LW(k) v4f W##k = { wp[(size_t)(4*(k)+0)*DH], wp[(size_t)(4*(k)+1)*DH], \
                           wp[(size_t)(4*(k)+2)*DH], wp[(size_t)(4*(k)+3)*DH] };
    LW(0) LW(1) LW(2) LW(3) LW(4) LW(5) LW(6) LW(7)
    LW(8) LW(9) LW(10) LW(11) LW(12) LW(13) LW(14) LW(15)
#undef LW

    const float* inp = (m == 0) ? x : outx;  // in-place after module 0

    // previous-module stores must land before we read the same addresses back
    asm volatile("s_waitcnt vmcnt(0)" ::: "memory");

    const float* pin  = inp  + ubase;   // uniform base, [lane] indexing
    float*       pout = outx + ubase;

    // prologue: stage in(0) into b0; pipeline holds in(1..3)
    b0[lane] = pin[lane];
    float vW = pin[lane + (size_t)1 * NCD];   // in(1) -> written at i=0
    float vA = pin[lane + (size_t)2 * NCD];
    float vB = pin[lane + (size_t)3 * NCD];
    const float* pf = pin + (size_t)4 * NCD;  // next prefetch target: in(4)

    auto step = [&](const float* rd, float* wr, int i) {
      // stage next step's input into the other buffer (no wait needed on rd:
      // its write happened a full iteration ago)
      wr[lane] = vW;

      // prefetch in(i+4), clamped (dummy in-bounds read near the end)
      const float* lp = (i < STEPS - 4) ? pf : pin;
      const float vN = lp[lane];
      pf += NCD;

      // keep W resident in arch VGPRs
      asm volatile("" : "+v"(W0), "+v"(W1), "+v"(W2),  "+v"(W3),
                       "+v"(W4), "+v"(W5), "+v"(W6),  "+v"(W7),
                       "+v"(W8), "+v"(W9), "+v"(W10), "+v"(W11),
                       "+v"(W12), "+v"(W13), "+v"(W14), "+v"(W15));

      // broadcast reads: same address across all 64 lanes (conflict-free)
      const v4f* rq = (const v4f*)rd;
      v4f q0 = rq[0],  q1 = rq[1],  q2 = rq[2],  q3 = rq[3];
      v4f q4 = rq[4],  q5 = rq[5],  q6 = rq[6],  q7 = rq[7];
      v4f q8 = rq[8],  q9 = rq[9],  q10 = rq[10], q11 = rq[11];
      v4f q12 = rq[12], q13 = rq[13], q14 = rq[14], q15 = rq[15];

      v4f acc0 = q0 * W0;
      v4f acc1 = q1 * W1;
      acc0 = __builtin_elementwise_fma(q2,  W2,  acc0);
      acc1 = __builtin_elementwise_fma(q3,  W3,  acc1);
      acc0 = __builtin_elementwise_fma(q4,  W4,  acc0);
      acc1 = __builtin_elementwise_fma(q5,  W5,  acc1);
      acc0 = __builtin_elementwise_fma(q6,  W6,  acc0);
      acc1 = __builtin_elementwise_fma(q7,  W7,  acc1);
      acc0 = __builtin_elementwise_fma(q8,  W8,  acc0);
      acc1 = __builtin_elementwise_fma(q9,  W9,  acc1);
      acc0 = __builtin_elementwise_fma(q10, W10, acc0);
      acc1 = __builtin_elementwise_fma(q11, W11, acc1);
      acc0 = __builtin_elementwise_fma(q12, W12, acc0);
      acc1 = __builtin_elementwise_fma(q13, W13, acc1);
      acc0 = __builtin_elementwise_fma(q14, W14, acc0);
      acc1 = __builtin_elementwise_fma(q15, W15, acc1);
      const v4f accs = acc0 + acc1;
      const float mix = (accs.x + accs.y) + (accs.z + accs.w);

      // y = tanh(0.5*y + 0.5*mix) = 1 - 2/(e^z + 1), z = y + mix
      const float z  = y + mix;
      const float ex = __expf(z);
      y = 1.0f - 2.0f * __builtin_amdgcn_rcpf(ex + 1.0f);

      pout[lane] = y;
      pout += NCD;

      vW = vA; vA = vB; vB = vN;
    };

    for (int i = 0; i < STEPS; i += 2) {
      step(b0, b1, i);
      step(b1, b0, i + 1);
    }
  }

  outya[((size_t)b * NC + c) * D + (size_t)h * DH + lane] = y;
}

extern "C" void kernel_launch(void* const* d_in, const int* in_sizes, int n_in,
                              void* d_out, int out_size, void* d_ws, size_t ws_size,
                              hipStream_t stream) {
  (void)in_sizes; (void)n_in; (void)d_ws; (void)ws_size; (void)out_size;
  const float* x  = (const float*)d_in[0];
  const float* xa = (const float*)d_in[1];
  const float* w  = (const float*)d_in[2];
  float* out = (float*)d_out;

  dim3 grid(256), block(256);
  hipLaunchKernelGGL(ncn_fused, grid, block, 0, stream, x, xa, w, out);
}

// Round 4
// 428.628 us; speedup vs baseline: 2.4632x; 1.6899x over previous
//
#include <hip/hip_runtime.h>

// NCN as 4x (GEMM + scan), 8 stream-ordered launches, all in-place in d_out.
// x: [8,4096,1024] f32, xa: [8,8,1024] f32, W: [4,16,64,64] f32.
// out = concat(final x [8,4096,1024], final xa [8,8,1024]).
// mix[b,t,h*64+e] = sum_d in[b,t,h*64+d] * W[m,h,d,e]   (parallel over t)
// scan: y[t] = tanh(0.5*cache + 0.5*mix[t]), cache = y[t-8]  (per (b,c,d) chain)

typedef float v2f __attribute__((ext_vector_type(2)));
typedef float v4f __attribute__((ext_vector_type(4)));

constexpr int B  = 8;
constexpr int T  = 4096;
constexpr int D  = 1024;
constexpr int H  = 16;
constexpr int DH = 64;
constexpr int NC = 8;
constexpr int NM = 4;

// ---------------- GEMM: one module, per-head row-block tiles ----------------
// grid: 4096 blocks = 32 t-tiles * 8 b * 16 h ; block 256 thr (4 waves)
// block tile: 128 rows x 64 cols (one head slice), in-place (stage rows first)
__global__ __launch_bounds__(256)
void gemm_mix(const float* __restrict__ in, float* __restrict__ buf,
              const float* __restrict__ w, float* __restrict__ yaStage) {
  __shared__ alignas(16) float Xs[128][68];  // +4 pad: 8-lane row-stride hits banks 0,4,..28
  __shared__ alignas(16) float Wt[64][68];   // W transposed: Wt[e][d]

  const int tid = threadIdx.x;
  const int bx  = blockIdx.x;
  const int h    = bx & 15;
  const int rb   = bx >> 4;
  const int b    = rb >> 5;
  const int tblk = rb & 31;                   // 128-row tile within this b
  const size_t row0 = (size_t)b * T + (size_t)tblk * 128;

  // stage X rows (this head's 64-col slice): 8 float4 per thread
#pragma unroll
  for (int j = 0; j < 8; ++j) {
    const int id  = tid + 256 * j;            // [0,2048)
    const int row = id >> 4;
    const int c4  = id & 15;
    const v4f v = *(const v4f*)&in[(row0 + row) * D + h * DH + c4 * 4];
    *(v4f*)&Xs[row][c4 * 4] = v;
  }
  // stage W transposed: W[m,h,d,e] -> Wt[e][d]; 4 float4 per thread
  const float* wh = w + (size_t)h * DH * DH;
#pragma unroll
  for (int j = 0; j < 4; ++j) {
    const int id = tid + 256 * j;             // [0,1024) float4 ids
    const int d  = id >> 4;
    const int e4 = (id & 15) * 4;
    const v4f v = *(const v4f*)&wh[d * DH + e4];
    Wt[e4 + 0][d] = v.x; Wt[e4 + 1][d] = v.y;
    Wt[e4 + 2][d] = v.z; Wt[e4 + 3][d] = v.w;
  }
  __syncthreads();

  // wave tile: 64 rows x 32 cols; lane r8 rows {r8+8j}, lane c4 cols {c4+8cc}
  const int wv = tid >> 6, lane = tid & 63;
  const int rbase = (wv & 1) * 64;
  const int cbase = (wv >> 1) * 32;
  const int r8 = lane >> 3, c4 = lane & 7;

  v2f acc[8][4];
#pragma unroll
  for (int j = 0; j < 8; ++j)
#pragma unroll
    for (int cc = 0; cc < 4; ++cc) acc[j][cc] = (v2f){0.f, 0.f};

#pragma unroll
  for (int kq = 0; kq < 16; ++kq) {
    v4f xr[8], wr[4];
#pragma unroll
    for (int j = 0; j < 8; ++j)  xr[j]  = *(const v4f*)&Xs[rbase + r8 + 8 * j][kq * 4];
#pragma unroll
    for (int cc = 0; cc < 4; ++cc) wr[cc] = *(const v4f*)&Wt[cbase + c4 + 8 * cc][kq * 4];
#pragma unroll
    for (int j = 0; j < 8; ++j)
#pragma unroll
      for (int cc = 0; cc < 4; ++cc) {
        acc[j][cc] = __builtin_elementwise_fma(xr[j].lo, wr[cc].lo, acc[j][cc]);
        acc[j][cc] = __builtin_elementwise_fma(xr[j].hi, wr[cc].hi, acc[j][cc]);
      }
  }

  // epilogue: in-place overwrite (reads are staged in LDS; our rows/cols only)
#pragma unroll
  for (int j = 0; j < 8; ++j) {
    const size_t row = row0 + rbase + r8 + 8 * j;
#pragma unroll
    for (int cc = 0; cc < 4; ++cc) {
      const int col = h * DH + cbase + c4 + 8 * cc;
      buf[row * D + col] = acc[j][cc].x + acc[j][cc].y;
    }
  }

  // tail copy: pre-GEMM y rows [T-8,T) -> yaStage (module m>0 cache init)
  if (yaStage != nullptr && tblk == 31) {
#pragma unroll
    for (int q = 0; q < 2; ++q) {
      const int id   = tid + 256 * q;         // [0,512)
      const int slot = id >> 6;
      const int col  = id & 63;
      yaStage[((size_t)b * NC + slot) * D + h * DH + col] = Xs[120 + slot][col];
    }
  }
}

// ---------------- scan: one module, 65536 independent chains ----------------
// grid 256 blocks x 256 thr; thread = (b, c, d); in-place on buf
__global__ __launch_bounds__(256)
void scan_mod(float* __restrict__ buf, const float* __restrict__ cinit,
              float* __restrict__ yaOut) {
  const int tid = threadIdx.x;
  const int bx  = blockIdx.x;
  const int b = bx >> 5;
  const int c = (bx >> 2) & 7;
  const int d = (bx & 3) * 256 + tid;

  float cache = cinit[((size_t)b * NC + c) * D + d];
  float* p = buf + ((size_t)b * T + c) * D + d;   // step s at p[s*8192]
  constexpr size_t ST = (size_t)NC * D;           // 8192

  float cur[8], nxt[8];
#pragma unroll
  for (int j = 0; j < 8; ++j) cur[j] = p[(size_t)j * ST];

  for (int k = 0; k < 64; ++k) {
    if (k < 63) {
      const size_t bn = (size_t)(k + 1) * 8 * ST;
#pragma unroll
      for (int j = 0; j < 8; ++j) nxt[j] = p[bn + (size_t)j * ST];
    }
#pragma unroll
    for (int j = 0; j < 8; ++j) {
      const float z = cache + cur[j];             // tanh(0.5(cache+mix))
      const float e = __expf(z);
      const float y = 1.0f - 2.0f * __builtin_amdgcn_rcpf(e + 1.0f);
      p[(size_t)(k * 8 + j) * ST] = y;
      cache = y;
    }
#pragma unroll
    for (int j = 0; j < 8; ++j) cur[j] = nxt[j];
  }
  if (yaOut) yaOut[((size_t)b * NC + c) * D + d] = cache;
}

extern "C" void kernel_launch(void* const* d_in, const int* in_sizes, int n_in,
                              void* d_out, int out_size, void* d_ws, size_t ws_size,
                              hipStream_t stream) {
  (void)in_sizes; (void)n_in; (void)d_ws; (void)ws_size; (void)out_size;
  const float* x  = (const float*)d_in[0];
  const float* xa = (const float*)d_in[1];
  const float* w  = (const float*)d_in[2];
  float* buf     = (float*)d_out;                        // [B,T,D], in-place
  float* yaStage = (float*)d_out + (size_t)B * T * D;    // [B,NC,D] ya region

  for (int m = 0; m < NM; ++m) {
    const float* wm = w + (size_t)m * H * DH * DH;
    hipLaunchKernelGGL(gemm_mix, dim3(4096), dim3(256), 0, stream,
                       (m == 0) ? x : buf, buf, wm,
                       (m > 0) ? yaStage : nullptr);
    hipLaunchKernelGGL(scan_mod, dim3(256), dim3(256), 0, stream,
                       buf, (m == 0) ? xa : yaStage,
                       (m == NM - 1) ? yaStage : nullptr);
  }
}

// Round 5
// 378.578 us; speedup vs baseline: 2.7888x; 1.1322x over previous
//
#include <hip/hip_runtime.h>

// NCN as 4x (MFMA-GEMM + scan), 8 launches, in-place in d_out, no LDS, no ws.
// x: [8,4096,1024] f32, xa: [8,8,1024] f32, W: [4,16,64,64] f32.
// mix[b,t,h*64+e] = sum_d in[b,t,h*64+d] * W[m,h,d,e]
// scan: y[t] = tanh(0.5*cache + 0.5*mix[t]), cache = y[t-8] per (b,c,d) chain;
// scan's final cache IS next module's cache init (= ya output of the module).
// GEMM in bf16 hi/lo (3 MFMA passes: hi*hi + hi*lo + lo*hi), error ~1e-4.

typedef short short8 __attribute__((ext_vector_type(8)));
typedef float f32x4  __attribute__((ext_vector_type(4)));

constexpr int B  = 8;
constexpr int T  = 4096;
constexpr int D  = 1024;
constexpr int H  = 16;
constexpr int DH = 64;
constexpr int NC = 8;
constexpr int NM = 4;

__device__ __forceinline__ short f2bf(float f) {          // RNE truncate
  unsigned u = __float_as_uint(f);
  return (short)((u + 0x7fffu + ((u >> 16) & 1u)) >> 16);
}
__device__ __forceinline__ float bf2f(short s) {
  return __uint_as_float(((unsigned)(unsigned short)s) << 16);
}

// grid: 4096 = (b:8, tblk:32, h:16); block 256 = 4 waves; wave tile 32x64.
// A-frag: row = lane&15, k-slot = (lane>>4)*8+e. B-frag: col = lane&15, same
// k-slots (consistent slot->k bijection on both operands => correct dot).
// C-frag (m89-verified): col = lane&15, row = (lane>>4)*4 + j.
__global__ __launch_bounds__(256)
void gemm_mix(const float* __restrict__ in, float* __restrict__ buf,
              const float* __restrict__ w) {
  const int tid  = threadIdx.x, lane = tid & 63, wv = tid >> 6;
  const int bx   = blockIdx.x;
  const int h    = bx & 15;
  const int rb   = bx >> 4;
  const int b    = rb >> 5;
  const int tblk = rb & 31;
  const int lr   = lane & 15;   // row (A) / col (B,C) within 16-tile
  const int lg   = lane >> 4;   // k-group / C row-group
  const size_t row0 = (size_t)b * T + (size_t)tblk * 128 + wv * 32;
  const float* wh = w + (size_t)h * DH * DH;   // [d][e] row-major

  // ---- B fragments (W), hi/lo: Bf[kt][nt], element e <-> k = kt*32+lg*8+e
  short8 Bhi[2][4], Blo[2][4];
#pragma unroll
  for (int kt = 0; kt < 2; ++kt)
#pragma unroll
    for (int nt = 0; nt < 4; ++nt)
#pragma unroll
      for (int e = 0; e < 8; ++e) {
        const float v = wh[(size_t)(kt * 32 + lg * 8 + e) * DH + nt * 16 + lr];
        const short hi = f2bf(v);
        Bhi[kt][nt][e] = hi;
        Blo[kt][nt][e] = f2bf(v - bf2f(hi));
      }

  // ---- A fragments (input rows), hi/lo: Af[mt][kt]
  short8 Ahi[2][2], Alo[2][2];
#pragma unroll
  for (int mt = 0; mt < 2; ++mt)
#pragma unroll
    for (int kt = 0; kt < 2; ++kt) {
      const float* pa = in + (row0 + mt * 16 + lr) * D + h * DH + kt * 32 + lg * 8;
      const f32x4 a0 = *(const f32x4*)pa;
      const f32x4 a1 = *(const f32x4*)(pa + 4);
#pragma unroll
      for (int e = 0; e < 4; ++e) {
        const short h0 = f2bf(a0[e]);
        Ahi[mt][kt][e] = h0;
        Alo[mt][kt][e] = f2bf(a0[e] - bf2f(h0));
        const short h1 = f2bf(a1[e]);
        Ahi[mt][kt][4 + e] = h1;
        Alo[mt][kt][4 + e] = f2bf(a1[e] - bf2f(h1));
      }
    }

  // ---- MFMA: acc[mt][nt] += A(row0+mt*16.., k) * B(k, h*64+nt*16..)
  f32x4 acc[2][4];
#pragma unroll
  for (int mt = 0; mt < 2; ++mt)
#pragma unroll
    for (int nt = 0; nt < 4; ++nt) acc[mt][nt] = (f32x4){0.f, 0.f, 0.f, 0.f};

#pragma unroll
  for (int kt = 0; kt < 2; ++kt)
#pragma unroll
    for (int mt = 0; mt < 2; ++mt)
#pragma unroll
      for (int nt = 0; nt < 4; ++nt) {
        acc[mt][nt] = __builtin_amdgcn_mfma_f32_16x16x32_bf16(
            Ahi[mt][kt], Bhi[kt][nt], acc[mt][nt], 0, 0, 0);
        acc[mt][nt] = __builtin_amdgcn_mfma_f32_16x16x32_bf16(
            Ahi[mt][kt], Blo[kt][nt], acc[mt][nt], 0, 0, 0);
        acc[mt][nt] = __builtin_amdgcn_mfma_f32_16x16x32_bf16(
            Alo[mt][kt], Bhi[kt][nt], acc[mt][nt], 0, 0, 0);
      }

  // ---- epilogue: in-place overwrite of our own rows (reads already consumed)
#pragma unroll
  for (int mt = 0; mt < 2; ++mt)
#pragma unroll
    for (int nt = 0; nt < 4; ++nt)
#pragma unroll
      for (int j = 0; j < 4; ++j)
        buf[(row0 + mt * 16 + lg * 4 + j) * D + h * DH + nt * 16 + lr] =
            acc[mt][nt][j];
}

// ---------------- scan: 65536 independent chains, in-place ----------------
// grid 256 x 256 thr; thread = (b, c, d). Final cache -> yaOut (= next cinit).
__global__ __launch_bounds__(256)
void scan_mod(float* __restrict__ buf, const float* __restrict__ cinit,
              float* __restrict__ yaOut) {
  const int tid = threadIdx.x;
  const int bx  = blockIdx.x;
  const int b = bx >> 5;
  const int c = (bx >> 2) & 7;
  const int d = (bx & 3) * 256 + tid;

  float cache = cinit[((size_t)b * NC + c) * D + d];
  float* p = buf + ((size_t)b * T + c) * D + d;   // step s at p[s*8192]
  constexpr size_t ST = (size_t)NC * D;           // 8192

  float cur[8], nxt[8];
#pragma unroll
  for (int j = 0; j < 8; ++j) cur[j] = p[(size_t)j * ST];

  for (int k = 0; k < 64; ++k) {
    if (k < 63) {
      const size_t bn = (size_t)(k + 1) * 8 * ST;
#pragma unroll
      for (int j = 0; j < 8; ++j) nxt[j] = p[bn + (size_t)j * ST];
    }
#pragma unroll
    for (int j = 0; j < 8; ++j) {
      const float z = cache + cur[j];             // tanh(0.5(cache+mix))
      const float e = __expf(z);
      const float y = 1.0f - 2.0f * __builtin_amdgcn_rcpf(e + 1.0f);
      p[(size_t)(k * 8 + j) * ST] = y;
      cache = y;
    }
#pragma unroll
    for (int j = 0; j < 8; ++j) cur[j] = nxt[j];
  }
  yaOut[((size_t)b * NC + c) * D + d] = cache;
}

extern "C" void kernel_launch(void* const* d_in, const int* in_sizes, int n_in,
                              void* d_out, int out_size, void* d_ws, size_t ws_size,
                              hipStream_t stream) {
  (void)in_sizes; (void)n_in; (void)d_ws; (void)ws_size; (void)out_size;
  const float* x  = (const float*)d_in[0];
  const float* xa = (const float*)d_in[1];
  const float* w  = (const float*)d_in[2];
  float* buf     = (float*)d_out;                        // [B,T,D], in-place
  float* yaStage = (float*)d_out + (size_t)B * T * D;    // [B,NC,D] ya region

  for (int m = 0; m < NM; ++m) {
    const float* wm = w + (size_t)m * H * DH * DH;
    hipLaunchKernelGGL(gemm_mix, dim3(4096), dim3(256), 0, stream,
                       (m == 0) ? x : buf, buf, wm);
    hipLaunchKernelGGL(scan_mod, dim3(256), dim3(256), 0, stream,
                       buf, (m == 0) ? xa : yaStage, yaStage);
  }
}

// Round 6
// 368.964 us; speedup vs baseline: 2.8615x; 1.0261x over previous
//
#include <hip/hip_runtime.h>

// NCN as 4x (MFMA-GEMM + scan), 8 launches, in-place in d_out, no LDS, no ws.
// x: [8,4096,1024] f32, xa: [8,8,1024] f32, W: [4,16,64,64] f32.
// mix[b,t,h*64+e] = sum_d in[b,t,h*64+d] * W[m,h,d,e]
// GEMM transposed onto MFMA: C'[i=e][j=t] = sum_d W[d][e] * X[t][d], so the
// C fragment holds 4 consecutive e-cols of one t-row per lane -> f32x4 stores.
// bf16 hi/lo 3-pass (hi*hi + hi*lo + lo*hi), mix error ~1e-4.
// scan: y[t] = tanh(0.5*cache + 0.5*mix[t]), cache = y[t-8] per (b,c,d) chain;
// scan's final cache IS next module's cache init (= ya output of the module).

typedef short short8 __attribute__((ext_vector_type(8)));
typedef float f32x4  __attribute__((ext_vector_type(4)));

constexpr int B  = 8;
constexpr int T  = 4096;
constexpr int D  = 1024;
constexpr int H  = 16;
constexpr int DH = 64;
constexpr int NC = 8;
constexpr int NM = 4;

__device__ __forceinline__ short f2bf(float f) {          // RNE
  unsigned u = __float_as_uint(f);
  return (short)((u + 0x7fffu + ((u >> 16) & 1u)) >> 16);
}
__device__ __forceinline__ float bf2f(short s) {
  return __uint_as_float(((unsigned)(unsigned short)s) << 16);
}

// grid: 1024 = (b:8, h:16, tc:8); block 256 = 4 waves; wave = 128 rows x 64 e.
// A'-frag (W): row i=e -> it*16+lr, k-slot d = kt*32+lg*8+eidx.
// B'-frag (X): col j=t -> jt*16+lr, same k-slot mapping.
// C'-frag: col j=t=lr, row i=e = it*16+lg*4+reg  -> f32x4 store per (it,jt).
__global__ __launch_bounds__(256, 2)
void gemm_mix(const float* __restrict__ in, float* __restrict__ buf,
              const float* __restrict__ w) {
  const int tid  = threadIdx.x, lane = tid & 63, wv = tid >> 6;
  const int bx   = blockIdx.x;
  const int tc   = bx & 7;
  const int h    = (bx >> 3) & 15;
  const int b    = bx >> 7;
  const int lr   = lane & 15;
  const int lg   = lane >> 4;
  const size_t row0 = (size_t)b * T + (size_t)tc * 512 + (size_t)wv * 128;
  const float* wh = w + (size_t)h * DH * DH;   // W[d][e] row-major

  // ---- W fragments (A-operand), hi/lo, loaded ONCE per wave (64 VGPR)
  short8 Whi[4][2], Wlo[4][2];
#pragma unroll
  for (int it = 0; it < 4; ++it)
#pragma unroll
    for (int kt = 0; kt < 2; ++kt)
#pragma unroll
      for (int e = 0; e < 8; ++e) {
        const float v = wh[(size_t)(kt * 32 + lg * 8 + e) * DH + it * 16 + lr];
        const short hi = f2bf(v);
        Whi[it][kt][e] = hi;
        Wlo[it][kt][e] = f2bf(v - bf2f(hi));
      }

  // ---- 4 iterations x 32 rows
#pragma unroll
  for (int i = 0; i < 4; ++i) {
    // X rows as B-operand (8 independent dwordx4 loads)
    f32x4 xr[2][2][2];
#pragma unroll
    for (int jt = 0; jt < 2; ++jt)
#pragma unroll
      for (int kt = 0; kt < 2; ++kt) {
        const float* pa =
            in + (row0 + i * 32 + jt * 16 + lr) * D + h * DH + kt * 32 + lg * 8;
        xr[jt][kt][0] = *(const f32x4*)pa;
        xr[jt][kt][1] = *(const f32x4*)(pa + 4);
      }

    short8 Xhi[2][2], Xlo[2][2];
#pragma unroll
    for (int jt = 0; jt < 2; ++jt)
#pragma unroll
      for (int kt = 0; kt < 2; ++kt)
#pragma unroll
        for (int q = 0; q < 2; ++q)
#pragma unroll
          for (int e = 0; e < 4; ++e) {
            const float v = xr[jt][kt][q][e];
            const short hi = f2bf(v);
            Xhi[jt][kt][q * 4 + e] = hi;
            Xlo[jt][kt][q * 4 + e] = f2bf(v - bf2f(hi));
          }

    f32x4 acc[4][2];
#pragma unroll
    for (int it = 0; it < 4; ++it)
#pragma unroll
      for (int jt = 0; jt < 2; ++jt) acc[it][jt] = (f32x4){0.f, 0.f, 0.f, 0.f};

#pragma unroll
    for (int kt = 0; kt < 2; ++kt)
#pragma unroll
      for (int it = 0; it < 4; ++it)
#pragma unroll
        for (int jt = 0; jt < 2; ++jt) {
          acc[it][jt] = __builtin_amdgcn_mfma_f32_16x16x32_bf16(
              Whi[it][kt], Xhi[jt][kt], acc[it][jt], 0, 0, 0);
          acc[it][jt] = __builtin_amdgcn_mfma_f32_16x16x32_bf16(
              Whi[it][kt], Xlo[jt][kt], acc[it][jt], 0, 0, 0);
          acc[it][jt] = __builtin_amdgcn_mfma_f32_16x16x32_bf16(
              Wlo[it][kt], Xhi[jt][kt], acc[it][jt], 0, 0, 0);
        }

    // vectorized in-place epilogue: one f32x4 per (it,jt)
#pragma unroll
    for (int jt = 0; jt < 2; ++jt)
#pragma unroll
      for (int it = 0; it < 4; ++it)
        *(f32x4*)&buf[(row0 + i * 32 + jt * 16 + lr) * D + h * DH + it * 16 +
                      lg * 4] = acc[it][jt];
  }
}

// ---------------- scan: 65536 independent chains, in-place ----------------
// grid 256 x 256 thr; thread = (b, c, d). Final cache -> yaOut (= next cinit).
__global__ __launch_bounds__(256)
void scan_mod(float* __restrict__ buf, const float* __restrict__ cinit,
              float* __restrict__ yaOut) {
  const int tid = threadIdx.x;
  const int bx  = blockIdx.x;
  const int b = bx >> 5;
  const int c = (bx >> 2) & 7;
  const int d = (bx & 3) * 256 + tid;

  float cache = cinit[((size_t)b * NC + c) * D + d];
  float* p = buf + ((size_t)b * T + c) * D + d;   // step s at p[s*8192]
  constexpr size_t ST = (size_t)NC * D;           // 8192

  float cur[8], nxt[8];
#pragma unroll
  for (int j = 0; j < 8; ++j) cur[j] = p[(size_t)j * ST];

  for (int k = 0; k < 64; ++k) {
    if (k < 63) {
      const size_t bn = (size_t)(k + 1) * 8 * ST;
#pragma unroll
      for (int j = 0; j < 8; ++j) nxt[j] = p[bn + (size_t)j * ST];
    }
#pragma unroll
    for (int j = 0; j < 8; ++j) {
      const float z = cache + cur[j];             // tanh(0.5(cache+mix))
      const float e = __expf(z);
      const float y = 1.0f - 2.0f * __builtin_amdgcn_rcpf(e + 1.0f);
      p[(size_t)(k * 8 + j) * ST] = y;
      cache = y;
    }
#pragma unroll
    for (int j = 0; j < 8; ++j) cur[j] = nxt[j];
  }
  yaOut[((size_t)b * NC + c) * D + d] = cache;
}

extern "C" void kernel_launch(void* const* d_in, const int* in_sizes, int n_in,
                              void* d_out, int out_size, void* d_ws, size_t ws_size,
                              hipStream_t stream) {
  (void)in_sizes; (void)n_in; (void)d_ws; (void)ws_size; (void)out_size;
  const float* x  = (const float*)d_in[0];
  const float* xa = (const float*)d_in[1];
  const float* w  = (const float*)d_in[2];
  float* buf     = (float*)d_out;                        // [B,T,D], in-place
  float* yaStage = (float*)d_out + (size_t)B * T * D;    // [B,NC,D] ya region

  for (int m = 0; m < NM; ++m) {
    const float* wm = w + (size_t)m * H * DH * DH;
    hipLaunchKernelGGL(gemm_mix, dim3(1024), dim3(256), 0, stream,
                       (m == 0) ? x : buf, buf, wm);
    hipLaunchKernelGGL(scan_mod, dim3(256), dim3(256), 0, stream,
                       buf, (m == 0) ? xa : yaStage, yaStage);
  }
}

// Round 7
// 330.315 us; speedup vs baseline: 3.1963x; 1.1170x over previous
//
#include <hip/hip_runtime.h>
#include <hip/hip_fp16.h>

// NCN as 4x (MFMA-GEMM + scan), 8 launches, in-place in d_out, no LDS, no ws.
// x: [8,4096,1024] f32, xa: [8,8,1024] f32, W: [4,16,64,64] f32.
// mix[b,t,h*64+e] = sum_d in[b,t,h*64+d] * W[m,h,d,e]
// KEY (round 6): mix is stored as packed f16 IN-PLACE inside buf so the whole
// inter-kernel footprint (134MB) fits the 256MB L3. Head h owns f32 cols
// [h*64,h*64+64) = bytes [h*256,+256) of each 4KB row; its 64 f16 mix values
// pack into the first 128B of that segment (ushort slots [h*128, h*128+64)).
// Scan reads f16 mix, overwrites the full row with f32 y.
// GEMM transposed onto MFMA: C'[i=e][j=t] = sum_d W[d][e] * X[t][d]; bf16
// hi/lo 3-pass (hi*hi + hi*lo + lo*hi), mix error ~1e-4 (+ f16 store ~2^-11).
// scan: y[t] = tanh(0.5*cache + 0.5*mix[t]), cache = y[t-8] per (b,c,d) chain;
// scan's final cache IS next module's cache init (= ya output of the module).

typedef short short8 __attribute__((ext_vector_type(8)));
typedef float f32x4  __attribute__((ext_vector_type(4)));

constexpr int B  = 8;
constexpr int T  = 4096;
constexpr int D  = 1024;
constexpr int H  = 16;
constexpr int DH = 64;
constexpr int NC = 8;
constexpr int NM = 4;

__device__ __forceinline__ short f2bf(float f) {          // RNE
  unsigned u = __float_as_uint(f);
  return (short)((u + 0x7fffu + ((u >> 16) & 1u)) >> 16);
}
__device__ __forceinline__ float bf2f(short s) {
  return __uint_as_float(((unsigned)(unsigned short)s) << 16);
}

// grid: 1024 = (b:8, h:16, tc:8); block 256 = 4 waves; wave = 128 rows x 64 e.
// A'-frag (W): row i=e -> it*16+lr, k-slot d = kt*32+lg*8+eidx.
// B'-frag (X): col j=t -> jt*16+lr, same k-slot mapping.
// C'-frag: col j=t=lr, row i=e = it*16+lg*4+reg.
__global__ __launch_bounds__(256, 2)
void gemm_mix(const float* __restrict__ in, float* __restrict__ buf,
              const float* __restrict__ w) {
  const int tid  = threadIdx.x, lane = tid & 63, wv = tid >> 6;
  const int bx   = blockIdx.x;
  const int tc   = bx & 7;
  const int h    = (bx >> 3) & 15;
  const int b    = bx >> 7;
  const int lr   = lane & 15;
  const int lg   = lane >> 4;
  const size_t row0 = (size_t)b * T + (size_t)tc * 512 + (size_t)wv * 128;
  const float* wh = w + (size_t)h * DH * DH;   // W[d][e] row-major

  // ---- W fragments (A-operand), hi/lo, loaded ONCE per wave (64 VGPR)
  short8 Whi[4][2], Wlo[4][2];
#pragma unroll
  for (int it = 0; it < 4; ++it)
#pragma unroll
    for (int kt = 0; kt < 2; ++kt)
#pragma unroll
      for (int e = 0; e < 8; ++e) {
        const float v = wh[(size_t)(kt * 32 + lg * 8 + e) * DH + it * 16 + lr];
        const short hi = f2bf(v);
        Whi[it][kt][e] = hi;
        Wlo[it][kt][e] = f2bf(v - bf2f(hi));
      }

  unsigned short* const mp = (unsigned short*)buf;   // packed f16 mix view

  // ---- 4 iterations x 32 rows
#pragma unroll
  for (int i = 0; i < 4; ++i) {
    // X rows as B-operand (8 independent dwordx4 loads)
    f32x4 xr[2][2][2];
#pragma unroll
    for (int jt = 0; jt < 2; ++jt)
#pragma unroll
      for (int kt = 0; kt < 2; ++kt) {
        const float* pa =
            in + (row0 + i * 32 + jt * 16 + lr) * D + h * DH + kt * 32 + lg * 8;
        xr[jt][kt][0] = *(const f32x4*)pa;
        xr[jt][kt][1] = *(const f32x4*)(pa + 4);
      }

    short8 Xhi[2][2], Xlo[2][2];
#pragma unroll
    for (int jt = 0; jt < 2; ++jt)
#pragma unroll
      for (int kt = 0; kt < 2; ++kt)
#pragma unroll
        for (int q = 0; q < 2; ++q)
#pragma unroll
          for (int e = 0; e < 4; ++e) {
            const float v = xr[jt][kt][q][e];
            const short hi = f2bf(v);
            Xhi[jt][kt][q * 4 + e] = hi;
            Xlo[jt][kt][q * 4 + e] = f2bf(v - bf2f(hi));
          }

    f32x4 acc[4][2];
#pragma unroll
    for (int it = 0; it < 4; ++it)
#pragma unroll
      for (int jt = 0; jt < 2; ++jt) acc[it][jt] = (f32x4){0.f, 0.f, 0.f, 0.f};

#pragma unroll
    for (int kt = 0; kt < 2; ++kt)
#pragma unroll
      for (int it = 0; it < 4; ++it)
#pragma unroll
        for (int jt = 0; jt < 2; ++jt) {
          acc[it][jt] = __builtin_amdgcn_mfma_f32_16x16x32_bf16(
              Whi[it][kt], Xhi[jt][kt], acc[it][jt], 0, 0, 0);
          acc[it][jt] = __builtin_amdgcn_mfma_f32_16x16x32_bf16(
              Whi[it][kt], Xlo[jt][kt], acc[it][jt], 0, 0, 0);
          acc[it][jt] = __builtin_amdgcn_mfma_f32_16x16x32_bf16(
              Wlo[it][kt], Xhi[jt][kt], acc[it][jt], 0, 0, 0);
        }

    // in-place packed-f16 epilogue: one 8B store per (it,jt), own rows only,
    // written into our own head's byte segment (subset of our read range).
#pragma unroll
    for (int jt = 0; jt < 2; ++jt)
#pragma unroll
      for (int it = 0; it < 4; ++it) {
        const f32x4 a = acc[it][jt];
        const __half2 h0 = __floats2half2_rn(a.x, a.y);
        const __half2 h1 = __floats2half2_rn(a.z, a.w);
        uint2 uv;
        uv.x = *(const unsigned*)&h0;
        uv.y = *(const unsigned*)&h1;
        const size_t row = row0 + i * 32 + jt * 16 + lr;
        *(uint2*)&mp[row * (2 * D) + h * 128 + it * 16 + lg * 4] = uv;
      }
  }
}

// ---------------- scan: 65536 independent chains, in-place ----------------
// grid 256 x 256 thr; thread = (b, c, d). Reads packed f16 mix, writes f32 y
// over the full row. Final cache -> yaOut (= next module's cinit).
__global__ __launch_bounds__(256)
void scan_mod(float* __restrict__ buf, const float* __restrict__ cinit,
              float* __restrict__ yaOut) {
  const int tid = threadIdx.x;
  const int bx  = blockIdx.x;
  const int b = bx >> 5;
  const int c = (bx >> 2) & 7;
  const int d = (bx & 3) * 256 + tid;

  float cache = cinit[((size_t)b * NC + c) * D + d];
  float* p = buf + ((size_t)b * T + c) * D + d;   // y store, step s at p[s*8192]
  const __half* q = (const __half*)buf;           // packed mix view
  const size_t base16 =
      ((size_t)b * T + c) * (size_t)(2 * D) + (size_t)((d >> 6) * 128 + (d & 63));
  constexpr size_t ST   = (size_t)NC * D;         // 8192 f32 (8 rows)
  constexpr size_t ST16 = (size_t)NC * 2 * D;     // 16384 ushort (8 rows)

  float cur[8], nxt[8];
#pragma unroll
  for (int j = 0; j < 8; ++j) cur[j] = __half2float(q[base16 + (size_t)j * ST16]);

  for (int k = 0; k < 64; ++k) {
    if (k < 63) {
#pragma unroll
      for (int j = 0; j < 8; ++j)
        nxt[j] = __half2float(q[base16 + (size_t)((k + 1) * 8 + j) * ST16]);
    }
#pragma unroll
    for (int j = 0; j < 8; ++j) {
      const float z = cache + cur[j];             // tanh(0.5(cache+mix))
      const float e = __expf(z);
      const float y = 1.0f - 2.0f * __builtin_amdgcn_rcpf(e + 1.0f);
      p[(size_t)(k * 8 + j) * ST] = y;
      cache = y;
    }
#pragma unroll
    for (int j = 0; j < 8; ++j) cur[j] = nxt[j];
  }
  yaOut[((size_t)b * NC + c) * D + d] = cache;
}

extern "C" void kernel_launch(void* const* d_in, const int* in_sizes, int n_in,
                              void* d_out, int out_size, void* d_ws, size_t ws_size,
                              hipStream_t stream) {
  (void)in_sizes; (void)n_in; (void)d_ws; (void)ws_size; (void)out_size;
  const float* x  = (const float*)d_in[0];
  const float* xa = (const float*)d_in[1];
  const float* w  = (const float*)d_in[2];
  float* buf     = (float*)d_out;                        // [B,T,D], in-place
  float* yaStage = (float*)d_out + (size_t)B * T * D;    // [B,NC,D] ya region

  for (int m = 0; m < NM; ++m) {
    const float* wm = w + (size_t)m * H * DH * DH;
    hipLaunchKernelGGL(gemm_mix, dim3(1024), dim3(256), 0, stream,
                       (m == 0) ? x : buf, buf, wm);
    hipLaunchKernelGGL(scan_mod, dim3(256), dim3(256), 0, stream,
                       buf, (m == 0) ? xa : yaStage, yaStage);
  }
}